// Round 7
// baseline (785.659 us; speedup 1.0000x reference)
//
#include <hip/hip_runtime.h>
#include <hip/hip_bf16.h>

#define MDIM 4096      // B*S tokens
#define DDIM 512
#define ADIM 64
#define HHEADS 8
#define SLEN 2048
#define TDIM 256
#define SPLIT 8

typedef __attribute__((ext_vector_type(8))) short short8;
typedef __attribute__((ext_vector_type(16))) float f32x16;

__device__ __forceinline__ unsigned short f2bf(float f) {
    union { __hip_bfloat16 h; unsigned short u; } c;
    c.h = __float2bfloat16(f);
    return c.u;
}
__device__ __forceinline__ float bf2f(short s) {
    return __uint_as_float((unsigned)(unsigned short)s << 16);
}

// ---------------------------------------------------------------------------
// prep: weights fp32 -> bf16 transposed; x -> bf16. Coalesced READS,
// scattered 2B stores.
// ---------------------------------------------------------------------------
#define N1 524288
#define N2 524288
#define NP 131072
__global__ __launch_bounds__(256) void prep_k(
    const float* __restrict__ Wq, const float* __restrict__ Wk, const float* __restrict__ Wv,
    const float* __restrict__ Wo, const float* __restrict__ W1, const float* __restrict__ W2,
    const float* __restrict__ Wp, const float* __restrict__ x,
    short* __restrict__ Wqt, short* __restrict__ Wkt, short* __restrict__ Wvt,
    short* __restrict__ Wot, short* __restrict__ W1t, short* __restrict__ W2t,
    short* __restrict__ Wpt, short* __restrict__ xbf)
{
    long idx = (long)blockIdx.x * 256 + threadIdx.x;
    if (idx < 3L * N1) {
        int t = (int)(idx / N1);
        int r = (int)(idx % N1);
        int a = r & 63, k = (r >> 6) & 511, hh = r >> 15;
        const float* src = (t == 0) ? Wq : (t == 1) ? Wk : Wv;
        short* dst = (t == 0) ? Wqt : (t == 1) ? Wkt : Wvt;
        dst[((size_t)hh << 15) + (a << 9) + k] = (short)f2bf(src[r]);
        return;
    }
    idx -= 3L * N1;
    if (idx < 3L * N2) {
        int t = (int)(idx / N2);
        int r = (int)(idx % N2);
        int n = r & 511, k = (r >> 9) & 511, i = r >> 18;
        const float* src = (t == 0) ? Wo : (t == 1) ? W1 : W2;
        short* dst = (t == 0) ? Wot : (t == 1) ? W1t : W2t;
        dst[((size_t)i << 18) + (n << 9) + k] = (short)f2bf(src[r]);
        return;
    }
    idx -= 3L * N2;
    if (idx < NP) {
        int r = (int)idx;
        int n = r & 255, k = r >> 8;
        Wpt[n * 512 + k] = (short)f2bf(Wp[r]);
        return;
    }
    idx -= NP;
    xbf[idx] = (short)f2bf(x[idx]);
}

// ---------------------------------------------------------------------------
// bf16 MFMA GEMM: C[M,N] = A[M,K] @ B + bias. B TRANSPOSED: Bt[n][k].
// Tile 64m x 64n, BK=64, 4 waves (2m x 2n), wave = 32x32.
// flags: 1=relu, 2=bf16 out.
// ---------------------------------------------------------------------------
#define LDT 66
__global__ __launch_bounds__(256, 2) void gemm_bf(
    const short* __restrict__ A, const short* __restrict__ Bt,
    const float* __restrict__ bias, void* __restrict__ Cout,
    int M, int N, int K, int flags)
{
    __shared__ short As[64 * LDT];
    __shared__ short Bs[64 * LDT];
    const int tid = threadIdx.x;
    const int wave = tid >> 6, lane = tid & 63;
    const int l31 = lane & 31, hi = lane >> 5;
    const int wm = wave >> 1, wn = wave & 1;
    const int m0 = blockIdx.y * 64, n0 = blockIdx.x * 64;

    f32x16 acc;
#pragma unroll
    for (int r = 0; r < 16; ++r) acc[r] = 0.f;

    const int sr = tid >> 2;
    const int sc = (tid & 3) * 16;

    for (int k0 = 0; k0 < K; k0 += 64) {
        __syncthreads();
        *(short8*)&As[sr * LDT + sc]     = *(const short8*)&A[(size_t)(m0 + sr) * K + k0 + sc];
        *(short8*)&As[sr * LDT + sc + 8] = *(const short8*)&A[(size_t)(m0 + sr) * K + k0 + sc + 8];
        *(short8*)&Bs[sr * LDT + sc]     = *(const short8*)&Bt[(size_t)(n0 + sr) * K + k0 + sc];
        *(short8*)&Bs[sr * LDT + sc + 8] = *(const short8*)&Bt[(size_t)(n0 + sr) * K + k0 + sc + 8];
        __syncthreads();

        short8 af[4], bfm[4];
#pragma unroll
        for (int ks = 0; ks < 4; ++ks) {
            af[ks]  = *(const short8*)&As[(wm * 32 + l31) * LDT + ks * 16 + hi * 8];
            bfm[ks] = *(const short8*)&Bs[(wn * 32 + l31) * LDT + ks * 16 + hi * 8];
        }
#pragma unroll
        for (int ks = 0; ks < 4; ++ks)
            acc = __builtin_amdgcn_mfma_f32_32x32x16_bf16(af[ks], bfm[ks], acc, 0, 0, 0);
    }

    const int col = n0 + wn * 32 + l31;
    const float bb = bias[col];
    const int rbase = m0 + wm * 32 + 4 * hi;
#pragma unroll
    for (int r = 0; r < 16; ++r) {
        int row = rbase + (r & 3) + 8 * (r >> 2);
        float v = acc[r] + bb;
        if (flags & 1) v = fmaxf(v, 0.f);
        if (flags & 2) ((short*)Cout)[(size_t)row * N + col] = (short)f2bf(v);
        else           ((float*)Cout)[(size_t)row * N + col] = v;
    }
}

// ---------------------------------------------------------------------------
// Fused QKV MFMA GEMM: A=xbf [4096,512]; grid (24 n-tiles, 32 m-tiles).
// Q pre-scaled by 0.125*log2(e); Q,K [bh][s][64] bf16; V transposed [bh][d][s].
// ---------------------------------------------------------------------------
#define EXPC 0.1803368801111244f   // 0.125 * log2(e)

__global__ __launch_bounds__(256, 2) void qkv_bf(
    const short* __restrict__ A,
    const short* __restrict__ Wqt, const short* __restrict__ Wkt, const short* __restrict__ Wvt,
    const float* __restrict__ bq, const float* __restrict__ bk, const float* __restrict__ bv,
    short* __restrict__ Oq, short* __restrict__ Ok, short* __restrict__ Ov)
{
    __shared__ short As[128 * LDT];
    __shared__ short Bs[64 * LDT];
    const int tid = threadIdx.x;
    const int wave = tid >> 6, lane = tid & 63;
    const int l31 = lane & 31, hi = lane >> 5;
    const int wm = wave >> 1, wn = wave & 1;
    const int m0 = blockIdx.y * 128;
    const int nt = blockIdx.x;
    const int which = nt >> 3, h = nt & 7;

    const short* Bt = ((which == 0) ? Wqt : (which == 1) ? Wkt : Wvt) + (size_t)h * 64 * 512;
    const float* bias = ((which == 0) ? bq : (which == 1) ? bk : bv) + h * 64;
    short* Out = (which == 0) ? Oq : (which == 1) ? Ok : Ov;

    f32x16 acc[2];
#pragma unroll
    for (int ms = 0; ms < 2; ++ms)
#pragma unroll
        for (int r = 0; r < 16; ++r) acc[ms][r] = 0.f;

    const int sr = tid >> 3;
    const int sc = (tid & 7) * 8;

    for (int k0 = 0; k0 < 512; k0 += 64) {
        __syncthreads();
#pragma unroll
        for (int p = 0; p < 4; ++p)
            *(short8*)&As[(p * 32 + sr) * LDT + sc] =
                *(const short8*)&A[(size_t)(m0 + p * 32 + sr) * 512 + k0 + sc];
#pragma unroll
        for (int p = 0; p < 2; ++p)
            *(short8*)&Bs[(p * 32 + sr) * LDT + sc] =
                *(const short8*)&Bt[(size_t)(p * 32 + sr) * 512 + k0 + sc];
        __syncthreads();

        short8 af[2][4], bfm[4];
#pragma unroll
        for (int ms = 0; ms < 2; ++ms)
#pragma unroll
            for (int ks = 0; ks < 4; ++ks)
                af[ms][ks] = *(const short8*)&As[(wm * 64 + ms * 32 + l31) * LDT + ks * 16 + hi * 8];
#pragma unroll
        for (int ks = 0; ks < 4; ++ks)
            bfm[ks] = *(const short8*)&Bs[(wn * 32 + l31) * LDT + ks * 16 + hi * 8];
#pragma unroll
        for (int ms = 0; ms < 2; ++ms)
#pragma unroll
            for (int ks = 0; ks < 4; ++ks)
                acc[ms] = __builtin_amdgcn_mfma_f32_32x32x16_bf16(af[ms][ks], bfm[ks], acc[ms], 0, 0, 0);
    }

    const int a = wn * 32 + l31;
    const float bb = bias[a];
    const int b = m0 >> 11;
    const int sb = (m0 & (SLEN - 1)) + wm * 64;
    const int bh = b * HHEADS + h;

    if (which == 0) {
        short* Ob = Out + (size_t)bh * SLEN * 64;
#pragma unroll
        for (int ms = 0; ms < 2; ++ms)
#pragma unroll
            for (int r = 0; r < 16; ++r) {
                int s = sb + ms * 32 + (r & 3) + 8 * (r >> 2) + 4 * hi;
                Ob[(size_t)s * 64 + a] = (short)f2bf((acc[ms][r] + bb) * EXPC);
            }
    } else if (which == 1) {
        short* Ob = Out + (size_t)bh * SLEN * 64;
#pragma unroll
        for (int ms = 0; ms < 2; ++ms)
#pragma unroll
            for (int r = 0; r < 16; ++r) {
                int s = sb + ms * 32 + (r & 3) + 8 * (r >> 2) + 4 * hi;
                Ob[(size_t)s * 64 + a] = (short)f2bf(acc[ms][r] + bb);
            }
    } else {
        short* Ob = Out + ((size_t)bh * 64 + a) * SLEN;
#pragma unroll
        for (int ms = 0; ms < 2; ++ms)
#pragma unroll
            for (int g = 0; g < 4; ++g) {
                int s = sb + ms * 32 + 8 * g + 4 * hi;
                ushort4 w;
                w.x = f2bf(acc[ms][4 * g + 0] + bb);
                w.y = f2bf(acc[ms][4 * g + 1] + bb);
                w.z = f2bf(acc[ms][4 * g + 2] + bb);
                w.w = f2bf(acc[ms][4 * g + 3] + bb);
                *(ushort4*)&Ob[s] = w;
            }
    }
}

// ---------------------------------------------------------------------------
// MFMA flash attention, no-max softmax (Q pre-scaled), key-split=8.
// grid (qt=8, bh=16, sp=8) = 1024 blocks = 4/CU; 4 waves/SIMD.
// ---------------------------------------------------------------------------
__global__ __launch_bounds__(256, 4) void attn_mfma(
    const short* __restrict__ Qb, const short* __restrict__ Kb,
    const short* __restrict__ Vtb, short* __restrict__ Op,
    float* __restrict__ lp)
{
    __shared__ short Ks[64 * 72];
    __shared__ short Vs[64 * 72];

    const int tid = threadIdx.x;
    const int wid = tid >> 6;
    const int lane = tid & 63;
    const int l31 = lane & 31;
    const int hi = lane >> 5;

    const int qt = blockIdx.x;
    const int bh = blockIdx.y;
    const int sp = blockIdx.z;

    const short* Qg = Qb + (size_t)bh * SLEN * 64;
    const short* Kg = Kb + (size_t)bh * SLEN * 64;
    const short* Vg = Vtb + (size_t)bh * 64 * SLEN;

    const int q0 = qt * 256 + wid * 64;

    short8 qf[2][4];
#pragma unroll
    for (int nt = 0; nt < 2; ++nt)
#pragma unroll
        for (int ks = 0; ks < 4; ++ks)
            qf[nt][ks] = *(const short8*)&Qg[(size_t)(q0 + nt * 32 + l31) * 64 + ks * 16 + hi * 8];

    f32x16 oacc[2][2], lacc[2];
#pragma unroll
    for (int nt = 0; nt < 2; ++nt) {
#pragma unroll
        for (int r = 0; r < 16; ++r) lacc[nt][r] = 0.f;
#pragma unroll
        for (int dt = 0; dt < 2; ++dt)
#pragma unroll
            for (int r = 0; r < 16; ++r) oacc[nt][dt][r] = 0.f;
    }

    short8 ones;
#pragma unroll
    for (int j = 0; j < 8; ++j) ones[j] = (short)0x3F80;   // bf16 1.0

    const int srow = tid >> 2;
    const int sch = (tid & 3) * 16;

    for (int kt = 0; kt < SLEN / SPLIT / 64; ++kt) {
        const int k0 = sp * (SLEN / SPLIT) + kt * 64;
        __syncthreads();
        *(short8*)&Ks[srow * 72 + sch]     = *(const short8*)&Kg[(size_t)(k0 + srow) * 64 + sch];
        *(short8*)&Ks[srow * 72 + sch + 8] = *(const short8*)&Kg[(size_t)(k0 + srow) * 64 + sch + 8];
        *(short8*)&Vs[srow * 72 + sch]     = *(const short8*)&Vg[(size_t)srow * SLEN + k0 + sch];
        *(short8*)&Vs[srow * 72 + sch + 8] = *(const short8*)&Vg[(size_t)srow * SLEN + k0 + sch + 8];
        __syncthreads();

        short8 kf[2][4], vf[2][4];
#pragma unroll
        for (int mt = 0; mt < 2; ++mt)
#pragma unroll
            for (int ks = 0; ks < 4; ++ks)
                kf[mt][ks] = *(const short8*)&Ks[(mt * 32 + l31) * 72 + ks * 16 + hi * 8];
#pragma unroll
        for (int dt = 0; dt < 2; ++dt)
#pragma unroll
            for (int p = 0; p < 4; ++p)
                vf[dt][p] = *(const short8*)&Vs[(dt * 32 + l31) * 72 + p * 16 + hi * 8];

#pragma unroll
        for (int nt = 0; nt < 2; ++nt) {
            f32x16 sacc[2];
#pragma unroll
            for (int mt = 0; mt < 2; ++mt) {
                f32x16 s;
#pragma unroll
                for (int r = 0; r < 16; ++r) s[r] = 0.f;
#pragma unroll
                for (int ks = 0; ks < 4; ++ks)
                    s = __builtin_amdgcn_mfma_f32_32x32x16_bf16(kf[mt][ks], qf[nt][ks], s, 0, 0, 0);
                sacc[mt] = s;
            }

            // p = exp2(s) (scale folded into Q); pack pairs via v_perm truncation
            int2 pk[2][4];
#pragma unroll
            for (int mt = 0; mt < 2; ++mt)
#pragma unroll
                for (int g = 0; g < 4; ++g) {
                    unsigned a0 = __float_as_uint(__builtin_amdgcn_exp2f(sacc[mt][4 * g + 0]));
                    unsigned a1 = __float_as_uint(__builtin_amdgcn_exp2f(sacc[mt][4 * g + 1]));
                    unsigned a2 = __float_as_uint(__builtin_amdgcn_exp2f(sacc[mt][4 * g + 2]));
                    unsigned a3 = __float_as_uint(__builtin_amdgcn_exp2f(sacc[mt][4 * g + 3]));
                    pk[mt][g].x = (int)__builtin_amdgcn_perm(a1, a0, 0x07060302u);
                    pk[mt][g].y = (int)__builtin_amdgcn_perm(a3, a2, 0x07060302u);
                }

            // minimal cross-half exchange: partner needs pk[2h2 + (1-hi)]
            int2 xch[2][2];
#pragma unroll
            for (int mt = 0; mt < 2; ++mt)
#pragma unroll
                for (int h2 = 0; h2 < 2; ++h2) {
                    int2 v = hi ? pk[mt][2 * h2] : pk[mt][2 * h2 + 1];
                    xch[mt][h2].x = __shfl_xor(v.x, 32);
                    xch[mt][h2].y = __shfl_xor(v.y, 32);
                }

#pragma unroll
            for (int p = 0; p < 4; ++p) {
                const int mt = p >> 1, h2 = p & 1;
                const int ga = 2 * h2, gb = 2 * h2 + 1;
                const int2 X = xch[mt][h2];
                union { int4 i; short8 s; } u;
                u.i.x = hi ? X.x : pk[mt][ga].x;
                u.i.y = hi ? X.y : pk[mt][ga].y;
                u.i.z = hi ? pk[mt][gb].x : X.x;
                u.i.w = hi ? pk[mt][gb].y : X.y;
                lacc[nt] = __builtin_amdgcn_mfma_f32_32x32x16_bf16(u.s, ones, lacc[nt], 0, 0, 0);
#pragma unroll
                for (int dt = 0; dt < 2; ++dt)
                    oacc[nt][dt] = __builtin_amdgcn_mfma_f32_32x32x16_bf16(u.s, vf[dt][p], oacc[nt][dt], 0, 0, 0);
            }
        }
    }

#pragma unroll
    for (int nt = 0; nt < 2; ++nt) {
        if (l31 == 0) {
#pragma unroll
            for (int r = 0; r < 16; ++r) {
                int qrow = (r & 3) + 8 * (r >> 2) + 4 * hi;
                lp[((size_t)(sp * 16 + bh)) * SLEN + q0 + nt * 32 + qrow] = lacc[nt][r];
            }
        }
#pragma unroll
        for (int dt = 0; dt < 2; ++dt) {
#pragma unroll
            for (int r = 0; r < 16; ++r) {
                int qrow = (r & 3) + 8 * (r >> 2) + 4 * hi;
                size_t addr = (((size_t)(sp * 16 + bh)) * SLEN + (q0 + nt * 32 + qrow)) * 64 + dt * 32 + l31;
                Op[addr] = (short)f2bf(oacc[nt][dt][r]);
            }
        }
    }
}

// ---------------------------------------------------------------------------
// Merge key-split partials -> hc bf16 [b,s, h*64+d]; 4 d-elems per thread
// ---------------------------------------------------------------------------
__global__ __launch_bounds__(256) void merge_k(
    const short* __restrict__ Op, const float* __restrict__ lp,
    short* __restrict__ hc)
{
    const int g = blockIdx.x * 256 + threadIdx.x;
    const int d4 = g & 15;
    const int s = (g >> 4) & (SLEN - 1);
    const int bh = g >> 15;

    float o[4] = {0.f, 0.f, 0.f, 0.f};
    float ls = 0.f;
#pragma unroll
    for (int sp = 0; sp < SPLIT; ++sp) {
        const size_t base = (((size_t)(sp * 16 + bh)) * SLEN + s);
        ushort4 u4 = *(const ushort4*)&Op[base * 64 + d4 * 4];
        o[0] += bf2f((short)u4.x); o[1] += bf2f((short)u4.y);
        o[2] += bf2f((short)u4.z); o[3] += bf2f((short)u4.w);
        ls += lp[base];
    }
    const int b = bh >> 3, h = bh & 7;
    const float inv = 1.f / ls;
    ushort4 w;
    w.x = f2bf(o[0] * inv); w.y = f2bf(o[1] * inv);
    w.z = f2bf(o[2] * inv); w.w = f2bf(o[3] * inv);
    *(ushort4*)&hc[((size_t)(b * SLEN + s)) * DDIM + h * 64 + d4 * 4] = w;
}

// ---------------------------------------------------------------------------
// AddNorm on bf16 stream: xbf = LN(xbf + y) * g + b ; y fp32.
// ---------------------------------------------------------------------------
__global__ __launch_bounds__(256) void addnorm_bf(
    short* __restrict__ X, const float* __restrict__ Y,
    const float* __restrict__ g, const float* __restrict__ beta)
{
    const int lane = threadIdx.x & 63;
    const int t = blockIdx.x * 4 + (threadIdx.x >> 6);
    short* xr = X + (size_t)t * DDIM;
    const float* yr = Y + (size_t)t * DDIM;
    const int c0 = lane * 8;

    short8 x8 = *(const short8*)&xr[c0];
    float4 y0 = *(const float4*)&yr[c0];
    float4 y1 = *(const float4*)&yr[c0 + 4];
    float v[8];
    v[0] = bf2f(x8[0]) + y0.x; v[1] = bf2f(x8[1]) + y0.y;
    v[2] = bf2f(x8[2]) + y0.z; v[3] = bf2f(x8[3]) + y0.w;
    v[4] = bf2f(x8[4]) + y1.x; v[5] = bf2f(x8[5]) + y1.y;
    v[6] = bf2f(x8[6]) + y1.z; v[7] = bf2f(x8[7]) + y1.w;

    float s1 = 0.f, s2 = 0.f;
#pragma unroll
    for (int j = 0; j < 8; ++j) { s1 += v[j]; s2 += v[j] * v[j]; }
#pragma unroll
    for (int off = 1; off < 64; off <<= 1) {
        s1 += __shfl_xor(s1, off);
        s2 += __shfl_xor(s2, off);
    }
    float mean = s1 * (1.0f / DDIM);
    float var = s2 * (1.0f / DDIM) - mean * mean;
    float rstd = rsqrtf(var + 1e-5f);

    float4 ga = *(const float4*)&g[c0];
    float4 gb = *(const float4*)&g[c0 + 4];
    float4 ba = *(const float4*)&beta[c0];
    float4 bb = *(const float4*)&beta[c0 + 4];
    float gg[8] = {ga.x, ga.y, ga.z, ga.w, gb.x, gb.y, gb.z, gb.w};
    float bt[8] = {ba.x, ba.y, ba.z, ba.w, bb.x, bb.y, bb.z, bb.w};

    short8 o8;
#pragma unroll
    for (int j = 0; j < 8; ++j)
        o8[j] = (short)f2bf((v[j] - mean) * rstd * gg[j] + bt[j]);
    *(short8*)&xr[c0] = o8;
}

// ---------------------------------------------------------------------------
// Workspace (MiB), FLAT layout (ws_size = 256 MiB per harness poison), 72 MiB:
//   [ 0, 4) xbf  [ 4, 8) Qbuf  [ 8,12) Kbuf  [12,16) Vtbuf  [16,20) hcbf
//   [20,28) y fp32  [28,32) hidbf  [32,64) Opart  [64,65) lpart
//   [65,72) weights bf16
// ---------------------------------------------------------------------------
extern "C" void kernel_launch(void* const* d_in, const int* in_sizes, int n_in,
                              void* d_out, int out_size, void* d_ws, size_t ws_size,
                              hipStream_t stream)
{
    (void)in_sizes; (void)n_in; (void)out_size; (void)ws_size;
    const float* x   = (const float*)d_in[0];
    const float* Wq  = (const float*)d_in[1];
    const float* bq  = (const float*)d_in[2];
    const float* Wk  = (const float*)d_in[3];
    const float* bk  = (const float*)d_in[4];
    const float* Wv  = (const float*)d_in[5];
    const float* bv  = (const float*)d_in[6];
    const float* Wo  = (const float*)d_in[7];
    const float* bo  = (const float*)d_in[8];
    const float* g1  = (const float*)d_in[9];
    const float* be1 = (const float*)d_in[10];
    const float* W1  = (const float*)d_in[11];
    const float* b1  = (const float*)d_in[12];
    const float* W2  = (const float*)d_in[13];
    const float* b2  = (const float*)d_in[14];
    const float* g2  = (const float*)d_in[15];
    const float* be2 = (const float*)d_in[16];
    const float* Wp  = (const float*)d_in[17];
    const float* bp  = (const float*)d_in[18];

    char* wsb = (char*)d_ws;
    const size_t MB = 1024 * 1024;
    short* xbf   = (short*)(wsb + 0);
    short* Qbuf  = (short*)(wsb + 4 * MB);
    short* Kbuf  = (short*)(wsb + 8 * MB);
    short* Vtbuf = (short*)(wsb + 12 * MB);
    short* hcbf  = (short*)(wsb + 16 * MB);
    float* y     = (float*)(wsb + 20 * MB);
    short* hidbf = (short*)(wsb + 28 * MB);
    short* Opart = (short*)(wsb + 32 * MB);
    float* lpart = (float*)(wsb + 64 * MB);
    short* Wqt   = (short*)(wsb + 65 * MB);
    short* Wkt   = (short*)(wsb + 66 * MB);
    short* Wvt   = (short*)(wsb + 67 * MB);
    short* Wot   = (short*)(wsb + 68 * MB);
    short* W1t   = (short*)(wsb + 69 * MB);
    short* W2t   = (short*)(wsb + 70 * MB);
    short* Wpt   = (short*)(wsb + 71 * MB);

    prep_k<<<20992, 256, 0, stream>>>(Wq, Wk, Wv, Wo, W1, W2, Wp, x,
                                      Wqt, Wkt, Wvt, Wot, W1t, W2t, Wpt, xbf);

    for (int i = 0; i < 2; ++i) {
        const size_t wOffQ = (size_t)i * 262144;
        const size_t wOffS = (size_t)i * 262144;
        qkv_bf<<<dim3(24, 32), 256, 0, stream>>>(
            xbf, Wqt + wOffQ, Wkt + wOffQ, Wvt + wOffQ,
            bq + i * 512, bk + i * 512, bv + i * 512,
            Qbuf, Kbuf, Vtbuf);
        attn_mfma<<<dim3(8, 16, SPLIT), 256, 0, stream>>>(Qbuf, Kbuf, Vtbuf, Opart, lpart);
        merge_k<<<2048, 256, 0, stream>>>(Opart, lpart, hcbf);
        gemm_bf<<<dim3(8, 64), 256, 0, stream>>>(
            hcbf, Wot + wOffS, bo + i * 512, y, MDIM, DDIM, DDIM, 0);
        addnorm_bf<<<1024, 256, 0, stream>>>(xbf, y, g1 + i * 512, be1 + i * 512);
        gemm_bf<<<dim3(8, 64), 256, 0, stream>>>(
            xbf, W1t + wOffS, b1 + i * 512, hidbf, MDIM, DDIM, DDIM, 3);
        gemm_bf<<<dim3(8, 64), 256, 0, stream>>>(
            hidbf, W2t + wOffS, b2 + i * 512, y, MDIM, DDIM, DDIM, 0);
        addnorm_bf<<<1024, 256, 0, stream>>>(xbf, y, g2 + i * 512, be2 + i * 512);
    }
    gemm_bf<<<dim3(4, 64), 256, 0, stream>>>(
        xbf, Wpt, bp, (float*)d_out, MDIM, TDIM, DDIM, 0);
}

// Round 8
// 304.151 us; speedup vs baseline: 2.5831x; 2.5831x over previous
//
#include <hip/hip_runtime.h>
#include <hip/hip_bf16.h>

#define MDIM 4096      // B*S tokens
#define DDIM 512
#define ADIM 64
#define HHEADS 8
#define SLEN 2048
#define TDIM 256
#define SPLIT 8

typedef __attribute__((ext_vector_type(8))) short short8;
typedef __attribute__((ext_vector_type(16))) float f32x16;

__device__ __forceinline__ unsigned short f2bf(float f) {
    union { __hip_bfloat16 h; unsigned short u; } c;
    c.h = __float2bfloat16(f);
    return c.u;
}
__device__ __forceinline__ float bf2f(short s) {
    return __uint_as_float((unsigned)(unsigned short)s << 16);
}

// ---------------------------------------------------------------------------
// prep: weights fp32 -> bf16 transposed; x -> bf16. Coalesced READS,
// scattered 2B stores.
// ---------------------------------------------------------------------------
#define N1 524288
#define N2 524288
#define NP 131072
__global__ __launch_bounds__(256) void prep_k(
    const float* __restrict__ Wq, const float* __restrict__ Wk, const float* __restrict__ Wv,
    const float* __restrict__ Wo, const float* __restrict__ W1, const float* __restrict__ W2,
    const float* __restrict__ Wp, const float* __restrict__ x,
    short* __restrict__ Wqt, short* __restrict__ Wkt, short* __restrict__ Wvt,
    short* __restrict__ Wot, short* __restrict__ W1t, short* __restrict__ W2t,
    short* __restrict__ Wpt, short* __restrict__ xbf)
{
    long idx = (long)blockIdx.x * 256 + threadIdx.x;
    if (idx < 3L * N1) {
        int t = (int)(idx / N1);
        int r = (int)(idx % N1);
        int a = r & 63, k = (r >> 6) & 511, hh = r >> 15;
        const float* src = (t == 0) ? Wq : (t == 1) ? Wk : Wv;
        short* dst = (t == 0) ? Wqt : (t == 1) ? Wkt : Wvt;
        dst[((size_t)hh << 15) + (a << 9) + k] = (short)f2bf(src[r]);
        return;
    }
    idx -= 3L * N1;
    if (idx < 3L * N2) {
        int t = (int)(idx / N2);
        int r = (int)(idx % N2);
        int n = r & 511, k = (r >> 9) & 511, i = r >> 18;
        const float* src = (t == 0) ? Wo : (t == 1) ? W1 : W2;
        short* dst = (t == 0) ? Wot : (t == 1) ? W1t : W2t;
        dst[((size_t)i << 18) + (n << 9) + k] = (short)f2bf(src[r]);
        return;
    }
    idx -= 3L * N2;
    if (idx < NP) {
        int r = (int)idx;
        int n = r & 255, k = r >> 8;
        Wpt[n * 512 + k] = (short)f2bf(Wp[r]);
        return;
    }
    idx -= NP;
    xbf[idx] = (short)f2bf(x[idx]);
}

// ---------------------------------------------------------------------------
// bf16 MFMA GEMM: C[M,N] = A[M,K] @ B + bias. B TRANSPOSED: Bt[n][k].
// Tile 64m x 64n, BK=64, 4 waves (2m x 2n), wave = 32x32.
// flags: 1=relu, 2=bf16 out.
// ---------------------------------------------------------------------------
#define LDT 66
__global__ __launch_bounds__(256, 2) void gemm_bf(
    const short* __restrict__ A, const short* __restrict__ Bt,
    const float* __restrict__ bias, void* __restrict__ Cout,
    int M, int N, int K, int flags)
{
    __shared__ short As[64 * LDT];
    __shared__ short Bs[64 * LDT];
    const int tid = threadIdx.x;
    const int wave = tid >> 6, lane = tid & 63;
    const int l31 = lane & 31, hi = lane >> 5;
    const int wm = wave >> 1, wn = wave & 1;
    const int m0 = blockIdx.y * 64, n0 = blockIdx.x * 64;

    f32x16 acc;
#pragma unroll
    for (int r = 0; r < 16; ++r) acc[r] = 0.f;

    const int sr = tid >> 2;
    const int sc = (tid & 3) * 16;

    for (int k0 = 0; k0 < K; k0 += 64) {
        __syncthreads();
        *(short8*)&As[sr * LDT + sc]     = *(const short8*)&A[(size_t)(m0 + sr) * K + k0 + sc];
        *(short8*)&As[sr * LDT + sc + 8] = *(const short8*)&A[(size_t)(m0 + sr) * K + k0 + sc + 8];
        *(short8*)&Bs[sr * LDT + sc]     = *(const short8*)&Bt[(size_t)(n0 + sr) * K + k0 + sc];
        *(short8*)&Bs[sr * LDT + sc + 8] = *(const short8*)&Bt[(size_t)(n0 + sr) * K + k0 + sc + 8];
        __syncthreads();

        short8 af[4], bfm[4];
#pragma unroll
        for (int ks = 0; ks < 4; ++ks) {
            af[ks]  = *(const short8*)&As[(wm * 32 + l31) * LDT + ks * 16 + hi * 8];
            bfm[ks] = *(const short8*)&Bs[(wn * 32 + l31) * LDT + ks * 16 + hi * 8];
        }
#pragma unroll
        for (int ks = 0; ks < 4; ++ks)
            acc = __builtin_amdgcn_mfma_f32_32x32x16_bf16(af[ks], bfm[ks], acc, 0, 0, 0);
    }

    const int col = n0 + wn * 32 + l31;
    const float bb = bias[col];
    const int rbase = m0 + wm * 32 + 4 * hi;
#pragma unroll
    for (int r = 0; r < 16; ++r) {
        int row = rbase + (r & 3) + 8 * (r >> 2);
        float v = acc[r] + bb;
        if (flags & 1) v = fmaxf(v, 0.f);
        if (flags & 2) ((short*)Cout)[(size_t)row * N + col] = (short)f2bf(v);
        else           ((float*)Cout)[(size_t)row * N + col] = v;
    }
}

// ---------------------------------------------------------------------------
// Fused QKV MFMA GEMM: A=xbf [4096,512]; grid (24 n-tiles, 32 m-tiles).
// Q pre-scaled by 0.125*log2(e); Q,K [bh][s][64] bf16; V transposed [bh][d][s].
// ---------------------------------------------------------------------------
#define EXPC 0.1803368801111244f   // 0.125 * log2(e)

__global__ __launch_bounds__(256, 2) void qkv_bf(
    const short* __restrict__ A,
    const short* __restrict__ Wqt, const short* __restrict__ Wkt, const short* __restrict__ Wvt,
    const float* __restrict__ bq, const float* __restrict__ bk, const float* __restrict__ bv,
    short* __restrict__ Oq, short* __restrict__ Ok, short* __restrict__ Ov)
{
    __shared__ short As[128 * LDT];
    __shared__ short Bs[64 * LDT];
    const int tid = threadIdx.x;
    const int wave = tid >> 6, lane = tid & 63;
    const int l31 = lane & 31, hi = lane >> 5;
    const int wm = wave >> 1, wn = wave & 1;
    const int m0 = blockIdx.y * 128;
    const int nt = blockIdx.x;
    const int which = nt >> 3, h = nt & 7;

    const short* Bt = ((which == 0) ? Wqt : (which == 1) ? Wkt : Wvt) + (size_t)h * 64 * 512;
    const float* bias = ((which == 0) ? bq : (which == 1) ? bk : bv) + h * 64;
    short* Out = (which == 0) ? Oq : (which == 1) ? Ok : Ov;

    f32x16 acc[2];
#pragma unroll
    for (int ms = 0; ms < 2; ++ms)
#pragma unroll
        for (int r = 0; r < 16; ++r) acc[ms][r] = 0.f;

    const int sr = tid >> 3;
    const int sc = (tid & 7) * 8;

    for (int k0 = 0; k0 < 512; k0 += 64) {
        __syncthreads();
#pragma unroll
        for (int p = 0; p < 4; ++p)
            *(short8*)&As[(p * 32 + sr) * LDT + sc] =
                *(const short8*)&A[(size_t)(m0 + p * 32 + sr) * 512 + k0 + sc];
#pragma unroll
        for (int p = 0; p < 2; ++p)
            *(short8*)&Bs[(p * 32 + sr) * LDT + sc] =
                *(const short8*)&Bt[(size_t)(p * 32 + sr) * 512 + k0 + sc];
        __syncthreads();

        short8 af[2][4], bfm[4];
#pragma unroll
        for (int ms = 0; ms < 2; ++ms)
#pragma unroll
            for (int ks = 0; ks < 4; ++ks)
                af[ms][ks] = *(const short8*)&As[(wm * 64 + ms * 32 + l31) * LDT + ks * 16 + hi * 8];
#pragma unroll
        for (int ks = 0; ks < 4; ++ks)
            bfm[ks] = *(const short8*)&Bs[(wn * 32 + l31) * LDT + ks * 16 + hi * 8];
#pragma unroll
        for (int ms = 0; ms < 2; ++ms)
#pragma unroll
            for (int ks = 0; ks < 4; ++ks)
                acc[ms] = __builtin_amdgcn_mfma_f32_32x32x16_bf16(af[ms][ks], bfm[ks], acc[ms], 0, 0, 0);
    }

    const int a = wn * 32 + l31;
    const float bb = bias[a];
    const int b = m0 >> 11;
    const int sb = (m0 & (SLEN - 1)) + wm * 64;
    const int bh = b * HHEADS + h;

    if (which == 0) {
        short* Ob = Out + (size_t)bh * SLEN * 64;
#pragma unroll
        for (int ms = 0; ms < 2; ++ms)
#pragma unroll
            for (int r = 0; r < 16; ++r) {
                int s = sb + ms * 32 + (r & 3) + 8 * (r >> 2) + 4 * hi;
                Ob[(size_t)s * 64 + a] = (short)f2bf((acc[ms][r] + bb) * EXPC);
            }
    } else if (which == 1) {
        short* Ob = Out + (size_t)bh * SLEN * 64;
#pragma unroll
        for (int ms = 0; ms < 2; ++ms)
#pragma unroll
            for (int r = 0; r < 16; ++r) {
                int s = sb + ms * 32 + (r & 3) + 8 * (r >> 2) + 4 * hi;
                Ob[(size_t)s * 64 + a] = (short)f2bf(acc[ms][r] + bb);
            }
    } else {
        short* Ob = Out + ((size_t)bh * 64 + a) * SLEN;
#pragma unroll
        for (int ms = 0; ms < 2; ++ms)
#pragma unroll
            for (int g = 0; g < 4; ++g) {
                int s = sb + ms * 32 + 8 * g + 4 * hi;
                ushort4 w;
                w.x = f2bf(acc[ms][4 * g + 0] + bb);
                w.y = f2bf(acc[ms][4 * g + 1] + bb);
                w.z = f2bf(acc[ms][4 * g + 2] + bb);
                w.w = f2bf(acc[ms][4 * g + 3] + bb);
                *(ushort4*)&Ob[s] = w;
            }
    }
}

// ---------------------------------------------------------------------------
// MFMA flash attention, no-max softmax (Q pre-scaled), key-split=8.
// grid (qt=8, bh=16, sp=8) = 1024 blocks; VGPR=128 naturally -> 4 blocks/CU.
// NOTE: launch_bounds min-waves stays 2 — forcing 4 caps VGPRs and spills
// (R7: VGPR 64, 935 MB scratch writes/dispatch, 2.6x slower).
// ---------------------------------------------------------------------------
__global__ __launch_bounds__(256, 2) void attn_mfma(
    const short* __restrict__ Qb, const short* __restrict__ Kb,
    const short* __restrict__ Vtb, short* __restrict__ Op,
    float* __restrict__ lp)
{
    __shared__ short Ks[64 * 72];
    __shared__ short Vs[64 * 72];

    const int tid = threadIdx.x;
    const int wid = tid >> 6;
    const int lane = tid & 63;
    const int l31 = lane & 31;
    const int hi = lane >> 5;

    const int qt = blockIdx.x;
    const int bh = blockIdx.y;
    const int sp = blockIdx.z;

    const short* Qg = Qb + (size_t)bh * SLEN * 64;
    const short* Kg = Kb + (size_t)bh * SLEN * 64;
    const short* Vg = Vtb + (size_t)bh * 64 * SLEN;

    const int q0 = qt * 256 + wid * 64;

    short8 qf[2][4];
#pragma unroll
    for (int nt = 0; nt < 2; ++nt)
#pragma unroll
        for (int ks = 0; ks < 4; ++ks)
            qf[nt][ks] = *(const short8*)&Qg[(size_t)(q0 + nt * 32 + l31) * 64 + ks * 16 + hi * 8];

    f32x16 oacc[2][2], lacc[2];
#pragma unroll
    for (int nt = 0; nt < 2; ++nt) {
#pragma unroll
        for (int r = 0; r < 16; ++r) lacc[nt][r] = 0.f;
#pragma unroll
        for (int dt = 0; dt < 2; ++dt)
#pragma unroll
            for (int r = 0; r < 16; ++r) oacc[nt][dt][r] = 0.f;
    }

    short8 ones;
#pragma unroll
    for (int j = 0; j < 8; ++j) ones[j] = (short)0x3F80;   // bf16 1.0

    const int srow = tid >> 2;
    const int sch = (tid & 3) * 16;

    for (int kt = 0; kt < SLEN / SPLIT / 64; ++kt) {
        const int k0 = sp * (SLEN / SPLIT) + kt * 64;
        __syncthreads();
        *(short8*)&Ks[srow * 72 + sch]     = *(const short8*)&Kg[(size_t)(k0 + srow) * 64 + sch];
        *(short8*)&Ks[srow * 72 + sch + 8] = *(const short8*)&Kg[(size_t)(k0 + srow) * 64 + sch + 8];
        *(short8*)&Vs[srow * 72 + sch]     = *(const short8*)&Vg[(size_t)srow * SLEN + k0 + sch];
        *(short8*)&Vs[srow * 72 + sch + 8] = *(const short8*)&Vg[(size_t)srow * SLEN + k0 + sch + 8];
        __syncthreads();

        short8 kf[2][4], vf[2][4];
#pragma unroll
        for (int mt = 0; mt < 2; ++mt)
#pragma unroll
            for (int ks = 0; ks < 4; ++ks)
                kf[mt][ks] = *(const short8*)&Ks[(mt * 32 + l31) * 72 + ks * 16 + hi * 8];
#pragma unroll
        for (int dt = 0; dt < 2; ++dt)
#pragma unroll
            for (int p = 0; p < 4; ++p)
                vf[dt][p] = *(const short8*)&Vs[(dt * 32 + l31) * 72 + p * 16 + hi * 8];

#pragma unroll
        for (int nt = 0; nt < 2; ++nt) {
            f32x16 sacc[2];
#pragma unroll
            for (int mt = 0; mt < 2; ++mt) {
                f32x16 s;
#pragma unroll
                for (int r = 0; r < 16; ++r) s[r] = 0.f;
#pragma unroll
                for (int ks = 0; ks < 4; ++ks)
                    s = __builtin_amdgcn_mfma_f32_32x32x16_bf16(kf[mt][ks], qf[nt][ks], s, 0, 0, 0);
                sacc[mt] = s;
            }

            // p = exp2(s) (scale folded into Q); pack pairs via v_perm truncation
            int2 pk[2][4];
#pragma unroll
            for (int mt = 0; mt < 2; ++mt)
#pragma unroll
                for (int g = 0; g < 4; ++g) {
                    unsigned a0 = __float_as_uint(__builtin_amdgcn_exp2f(sacc[mt][4 * g + 0]));
                    unsigned a1 = __float_as_uint(__builtin_amdgcn_exp2f(sacc[mt][4 * g + 1]));
                    unsigned a2 = __float_as_uint(__builtin_amdgcn_exp2f(sacc[mt][4 * g + 2]));
                    unsigned a3 = __float_as_uint(__builtin_amdgcn_exp2f(sacc[mt][4 * g + 3]));
                    pk[mt][g].x = (int)__builtin_amdgcn_perm(a1, a0, 0x07060302u);
                    pk[mt][g].y = (int)__builtin_amdgcn_perm(a3, a2, 0x07060302u);
                }

            // minimal cross-half exchange: partner needs pk[2h2 + (1-hi)]
            int2 xch[2][2];
#pragma unroll
            for (int mt = 0; mt < 2; ++mt)
#pragma unroll
                for (int h2 = 0; h2 < 2; ++h2) {
                    int2 v = hi ? pk[mt][2 * h2] : pk[mt][2 * h2 + 1];
                    xch[mt][h2].x = __shfl_xor(v.x, 32);
                    xch[mt][h2].y = __shfl_xor(v.y, 32);
                }

#pragma unroll
            for (int p = 0; p < 4; ++p) {
                const int mt = p >> 1, h2 = p & 1;
                const int ga = 2 * h2, gb = 2 * h2 + 1;
                const int2 X = xch[mt][h2];
                union { int4 i; short8 s; } u;
                u.i.x = hi ? X.x : pk[mt][ga].x;
                u.i.y = hi ? X.y : pk[mt][ga].y;
                u.i.z = hi ? pk[mt][gb].x : X.x;
                u.i.w = hi ? pk[mt][gb].y : X.y;
                lacc[nt] = __builtin_amdgcn_mfma_f32_32x32x16_bf16(u.s, ones, lacc[nt], 0, 0, 0);
#pragma unroll
                for (int dt = 0; dt < 2; ++dt)
                    oacc[nt][dt] = __builtin_amdgcn_mfma_f32_32x32x16_bf16(u.s, vf[dt][p], oacc[nt][dt], 0, 0, 0);
            }
        }
    }

#pragma unroll
    for (int nt = 0; nt < 2; ++nt) {
        if (l31 == 0) {
#pragma unroll
            for (int r = 0; r < 16; ++r) {
                int qrow = (r & 3) + 8 * (r >> 2) + 4 * hi;
                lp[((size_t)(sp * 16 + bh)) * SLEN + q0 + nt * 32 + qrow] = lacc[nt][r];
            }
        }
#pragma unroll
        for (int dt = 0; dt < 2; ++dt) {
#pragma unroll
            for (int r = 0; r < 16; ++r) {
                int qrow = (r & 3) + 8 * (r >> 2) + 4 * hi;
                size_t addr = (((size_t)(sp * 16 + bh)) * SLEN + (q0 + nt * 32 + qrow)) * 64 + dt * 32 + l31;
                Op[addr] = (short)f2bf(oacc[nt][dt][r]);
            }
        }
    }
}

// ---------------------------------------------------------------------------
// Merge key-split partials -> hc bf16 [b,s, h*64+d]; 4 d-elems per thread
// ---------------------------------------------------------------------------
__global__ __launch_bounds__(256) void merge_k(
    const short* __restrict__ Op, const float* __restrict__ lp,
    short* __restrict__ hc)
{
    const int g = blockIdx.x * 256 + threadIdx.x;
    const int d4 = g & 15;
    const int s = (g >> 4) & (SLEN - 1);
    const int bh = g >> 15;

    float o[4] = {0.f, 0.f, 0.f, 0.f};
    float ls = 0.f;
#pragma unroll
    for (int sp = 0; sp < SPLIT; ++sp) {
        const size_t base = (((size_t)(sp * 16 + bh)) * SLEN + s);
        ushort4 u4 = *(const ushort4*)&Op[base * 64 + d4 * 4];
        o[0] += bf2f((short)u4.x); o[1] += bf2f((short)u4.y);
        o[2] += bf2f((short)u4.z); o[3] += bf2f((short)u4.w);
        ls += lp[base];
    }
    const int b = bh >> 3, h = bh & 7;
    const float inv = 1.f / ls;
    ushort4 w;
    w.x = f2bf(o[0] * inv); w.y = f2bf(o[1] * inv);
    w.z = f2bf(o[2] * inv); w.w = f2bf(o[3] * inv);
    *(ushort4*)&hc[((size_t)(b * SLEN + s)) * DDIM + h * 64 + d4 * 4] = w;
}

// ---------------------------------------------------------------------------
// AddNorm on bf16 stream: xbf = LN(xbf + y) * g + b ; y fp32.
// ---------------------------------------------------------------------------
__global__ __launch_bounds__(256) void addnorm_bf(
    short* __restrict__ X, const float* __restrict__ Y,
    const float* __restrict__ g, const float* __restrict__ beta)
{
    const int lane = threadIdx.x & 63;
    const int t = blockIdx.x * 4 + (threadIdx.x >> 6);
    short* xr = X + (size_t)t * DDIM;
    const float* yr = Y + (size_t)t * DDIM;
    const int c0 = lane * 8;

    short8 x8 = *(const short8*)&xr[c0];
    float4 y0 = *(const float4*)&yr[c0];
    float4 y1 = *(const float4*)&yr[c0 + 4];
    float v[8];
    v[0] = bf2f(x8[0]) + y0.x; v[1] = bf2f(x8[1]) + y0.y;
    v[2] = bf2f(x8[2]) + y0.z; v[3] = bf2f(x8[3]) + y0.w;
    v[4] = bf2f(x8[4]) + y1.x; v[5] = bf2f(x8[5]) + y1.y;
    v[6] = bf2f(x8[6]) + y1.z; v[7] = bf2f(x8[7]) + y1.w;

    float s1 = 0.f, s2 = 0.f;
#pragma unroll
    for (int j = 0; j < 8; ++j) { s1 += v[j]; s2 += v[j] * v[j]; }
#pragma unroll
    for (int off = 1; off < 64; off <<= 1) {
        s1 += __shfl_xor(s1, off);
        s2 += __shfl_xor(s2, off);
    }
    float mean = s1 * (1.0f / DDIM);
    float var = s2 * (1.0f / DDIM) - mean * mean;
    float rstd = rsqrtf(var + 1e-5f);

    float4 ga = *(const float4*)&g[c0];
    float4 gb = *(const float4*)&g[c0 + 4];
    float4 ba = *(const float4*)&beta[c0];
    float4 bb = *(const float4*)&beta[c0 + 4];
    float gg[8] = {ga.x, ga.y, ga.z, ga.w, gb.x, gb.y, gb.z, gb.w};
    float bt[8] = {ba.x, ba.y, ba.z, ba.w, bb.x, bb.y, bb.z, bb.w};

    short8 o8;
#pragma unroll
    for (int j = 0; j < 8; ++j)
        o8[j] = (short)f2bf((v[j] - mean) * rstd * gg[j] + bt[j]);
    *(short8*)&xr[c0] = o8;
}

// ---------------------------------------------------------------------------
// Workspace (MiB), FLAT layout, 72 MiB (ws_size = 256 MiB):
//   [ 0, 4) xbf  [ 4, 8) Qbuf  [ 8,12) Kbuf  [12,16) Vtbuf  [16,20) hcbf
//   [20,28) y fp32  [28,32) hidbf  [32,64) Opart  [64,65) lpart
//   [65,72) weights bf16
// ---------------------------------------------------------------------------
extern "C" void kernel_launch(void* const* d_in, const int* in_sizes, int n_in,
                              void* d_out, int out_size, void* d_ws, size_t ws_size,
                              hipStream_t stream)
{
    (void)in_sizes; (void)n_in; (void)out_size; (void)ws_size;
    const float* x   = (const float*)d_in[0];
    const float* Wq  = (const float*)d_in[1];
    const float* bq  = (const float*)d_in[2];
    const float* Wk  = (const float*)d_in[3];
    const float* bk  = (const float*)d_in[4];
    const float* Wv  = (const float*)d_in[5];
    const float* bv  = (const float*)d_in[6];
    const float* Wo  = (const float*)d_in[7];
    const float* bo  = (const float*)d_in[8];
    const float* g1  = (const float*)d_in[9];
    const float* be1 = (const float*)d_in[10];
    const float* W1  = (const float*)d_in[11];
    const float* b1  = (const float*)d_in[12];
    const float* W2  = (const float*)d_in[13];
    const float* b2  = (const float*)d_in[14];
    const float* g2  = (const float*)d_in[15];
    const float* be2 = (const float*)d_in[16];
    const float* Wp  = (const float*)d_in[17];
    const float* bp  = (const float*)d_in[18];

    char* wsb = (char*)d_ws;
    const size_t MB = 1024 * 1024;
    short* xbf   = (short*)(wsb + 0);
    short* Qbuf  = (short*)(wsb + 4 * MB);
    short* Kbuf  = (short*)(wsb + 8 * MB);
    short* Vtbuf = (short*)(wsb + 12 * MB);
    short* hcbf  = (short*)(wsb + 16 * MB);
    float* y     = (float*)(wsb + 20 * MB);
    short* hidbf = (short*)(wsb + 28 * MB);
    short* Opart = (short*)(wsb + 32 * MB);
    float* lpart = (float*)(wsb + 64 * MB);
    short* Wqt   = (short*)(wsb + 65 * MB);
    short* Wkt   = (short*)(wsb + 66 * MB);
    short* Wvt   = (short*)(wsb + 67 * MB);
    short* Wot   = (short*)(wsb + 68 * MB);
    short* W1t   = (short*)(wsb + 69 * MB);
    short* W2t   = (short*)(wsb + 70 * MB);
    short* Wpt   = (short*)(wsb + 71 * MB);

    prep_k<<<20992, 256, 0, stream>>>(Wq, Wk, Wv, Wo, W1, W2, Wp, x,
                                      Wqt, Wkt, Wvt, Wot, W1t, W2t, Wpt, xbf);

    for (int i = 0; i < 2; ++i) {
        const size_t wOffQ = (size_t)i * 262144;
        const size_t wOffS = (size_t)i * 262144;
        qkv_bf<<<dim3(24, 32), 256, 0, stream>>>(
            xbf, Wqt + wOffQ, Wkt + wOffQ, Wvt + wOffQ,
            bq + i * 512, bk + i * 512, bv + i * 512,
            Qbuf, Kbuf, Vtbuf);
        attn_mfma<<<dim3(8, 16, SPLIT), 256, 0, stream>>>(Qbuf, Kbuf, Vtbuf, Opart, lpart);
        merge_k<<<2048, 256, 0, stream>>>(Opart, lpart, hcbf);
        gemm_bf<<<dim3(8, 64), 256, 0, stream>>>(
            hcbf, Wot + wOffS, bo + i * 512, y, MDIM, DDIM, DDIM, 0);
        addnorm_bf<<<1024, 256, 0, stream>>>(xbf, y, g1 + i * 512, be1 + i * 512);
        gemm_bf<<<dim3(8, 64), 256, 0, stream>>>(
            xbf, W1t + wOffS, b1 + i * 512, hidbf, MDIM, DDIM, DDIM, 3);
        gemm_bf<<<dim3(8, 64), 256, 0, stream>>>(
            hidbf, W2t + wOffS, b2 + i * 512, y, MDIM, DDIM, DDIM, 0);
        addnorm_bf<<<1024, 256, 0, stream>>>(xbf, y, g2 + i * 512, be2 + i * 512);
    }
    gemm_bf<<<dim3(4, 64), 256, 0, stream>>>(
        xbf, Wpt, bp, (float*)d_out, MDIM, TDIM, DDIM, 0);
}